// Round 11
// baseline (684.389 us; speedup 1.0000x reference)
//
#include <hip/hip_runtime.h>
#include <hip/hip_fp16.h>

#define NB 4
#define NR 256
#define NC 256
#define NCOIL 32
#define NSEG 4
#define NPOL 2
#define OD 276
#define OFF 10

typedef float2 c32;

__device__ __forceinline__ c32 cmul(c32 a, c32 b){
  return make_float2(a.x*b.x - a.y*b.y, a.x*b.y + a.y*b.x);
}
__device__ __forceinline__ c32 cmulj(c32 a, c32 b){ // a * conj(b)
  return make_float2(a.x*b.x + a.y*b.y, a.y*b.x - a.x*b.y);
}
__device__ __forceinline__ c32 cmulc(c32 a, float br, float bi){
  return make_float2(a.x*br - a.y*bi, a.x*bi + a.y*br);
}
__device__ __forceinline__ void wsync(){ __builtin_amdgcn_wave_barrier(); }

#define C16A 0.9238795325112867f
#define S16A 0.3826834323650898f
#define RSQ2 0.7071067811865476f

// radix-4: out[c] = sum_a in[a] * W4^{a c}; W4 = -i fwd, +i inv
template<int DIR>
__device__ __forceinline__ void r4(c32 a0, c32 a1, c32 a2, c32 a3,
                                   c32& o0, c32& o1, c32& o2, c32& o3){
  c32 s0 = make_float2(a0.x+a2.x, a0.y+a2.y);
  c32 d0 = make_float2(a0.x-a2.x, a0.y-a2.y);
  c32 s1 = make_float2(a1.x+a3.x, a1.y+a3.y);
  c32 d1 = make_float2(a1.x-a3.x, a1.y-a3.y);
  o0 = make_float2(s0.x+s1.x, s0.y+s1.y);
  o2 = make_float2(s0.x-s1.x, s0.y-s1.y);
  if (DIR > 0){
    o1 = make_float2(d0.x + d1.y, d0.y - d1.x);  // d0 - i*d1
    o3 = make_float2(d0.x - d1.y, d0.y + d1.x);
  } else {
    o1 = make_float2(d0.x - d1.y, d0.y + d1.x);
    o3 = make_float2(d0.x + d1.y, d0.y - d1.x);
  }
}

// in-register 16-pt DFT: y[k] = sum_n y[n] W16^{DIR * n k}, fully unrolled
template<int DIR>
__device__ __forceinline__ void dft16(c32* y){
  const float sg = (DIR > 0) ? -1.0f : 1.0f;
  c32 g[16];
  #pragma unroll
  for (int b = 0; b < 4; ++b)
    r4<DIR>(y[b], y[b+4], y[b+8], y[b+12], g[b], g[4+b], g[8+b], g[12+b]);
  // g[4c+b] *= W16^{bc}
  g[5]  = cmulc(g[5],  C16A,  sg*S16A);   // W^1
  g[6]  = cmulc(g[6],  RSQ2,  sg*RSQ2);   // W^2
  g[7]  = cmulc(g[7],  S16A,  sg*C16A);   // W^3
  g[9]  = cmulc(g[9],  RSQ2,  sg*RSQ2);   // W^2
  g[10] = cmulc(g[10], 0.0f,  sg);        // W^4
  g[11] = cmulc(g[11], -RSQ2, sg*RSQ2);   // W^6
  g[13] = cmulc(g[13], S16A,  sg*C16A);   // W^3
  g[14] = cmulc(g[14], -RSQ2, sg*RSQ2);   // W^6
  g[15] = cmulc(g[15], -C16A, -sg*S16A);  // W^9
  #pragma unroll
  for (int c = 0; c < 4; ++c)
    r4<DIR>(g[4*c], g[4*c+1], g[4*c+2], g[4*c+3],
            y[c], y[c+4], y[c+8], y[c+12]);
}

// per-lane step-2 twiddle table: tw[r] = W256^{l*r} (W = e^{-2pi i/256})
__device__ __forceinline__ void mk_tw16(int l, c32* tw){
  float sn, cs;
  sincosf(-0.0245436926061703f * (float)l, &sn, &cs);
  c32 base = make_float2(cs, sn);
  tw[0] = make_float2(1.0f, 0.0f);
  #pragma unroll
  for (int r = 1; r < 16; ++r) tw[r] = cmul(tw[r-1], base);
}

// 256-pt FFT as 16x16: 4 FFTs per wave (one per 16-lane group g), lane l.
// Fwd:  in  T-layout  y[i] = x[16i+l]   -> out K-layout y[j] = X[l+16j]
// Inv:  in  K-layout  y[j] = X[l+16j]   -> out T-layout y[i] = x[16i+l] (unnorm)
// ONE LDS exchange (XOR-swizzled 16x16 transpose per group) in fp16:
// sc = 1024 half2 per wave (4 KB).  Wave-synchronous.
template<int DIR>
__device__ __forceinline__ void fft256g(c32* y, const c32* tw, __half2* sc,
                                        int l, int g){
  dft16<DIR>(y);
  #pragma unroll
  for (int r = 1; r < 16; ++r)
    y[r] = (DIR > 0) ? cmul(y[r], tw[r]) : cmulj(y[r], tw[r]);
  #pragma unroll
  for (int r = 0; r < 16; ++r)
    sc[((r*4 + g) << 4) + (l ^ r)] = __floats2half2_rn(y[r].x, y[r].y);
  wsync();
  #pragma unroll
  for (int j = 0; j < 16; ++j)
    y[j] = __half22float2(sc[((l*4 + g) << 4) + (j ^ l)]);
  wsync();
  dft16<DIR>(y);
}

// ---------------------------------------------------------------------------
__global__ __launch_bounds__(256) void zero_kernel(float* __restrict__ out, int n){
  int i = blockIdx.x*256 + threadIdx.x;
  if (i < n) out[i] = 0.0f;
}

// ---------------------------------------------------------------------------
// pack_common: img_t[bl][pol][r][c] = crop(x)*(-1)^{r+c}/256 ;
// w_t[bl][pol*4+seg][r][c]; m_t[bl][pol*4+seg][c][r].
__global__ __launch_bounds__(256) void pack_common_kernel(
    const float* __restrict__ x_re, const float* __restrict__ x_im,
    const float* __restrict__ wm_re, const float* __restrict__ wm_im,
    const float* __restrict__ mask,
    c32* __restrict__ img_t, c32* __restrict__ w_t, float* __restrict__ m_t)
{
  int r = blockIdx.x & (NR-1);
  int bl = blockIdx.x >> 8;
  int c = threadIdx.x;
  const size_t PL = (size_t)NR*NC;
  float sc = (((r + c) & 1) ? -1.0f : 1.0f) * (1.0f/256.0f);
  size_t xrow = (((size_t)bl*OD) + (r+OFF))*OD + (c+OFF);
  #pragma unroll
  for (int pol = 0; pol < NPOL; ++pol){
    size_t xi = xrow*NPOL + pol;
    img_t[((size_t)(bl*NPOL+pol))*PL + (size_t)r*NC + c] =
        make_float2(x_re[xi]*sc, x_im[xi]*sc);
  }
  size_t wbase = (((size_t)bl*NR + r)*NC + c)*(NPOL*NSEG);
  const float4* wre4 = (const float4*)&wm_re[wbase];
  const float4* wim4 = (const float4*)&wm_im[wbase];
  const float4* mk4  = (const float4*)&mask[wbase];
  #pragma unroll
  for (int pol = 0; pol < NPOL; ++pol){
    float4 re = wre4[pol], im = wim4[pol], mk = mk4[pol];
    float rr[4] = {re.x, re.y, re.z, re.w};
    float ii[4] = {im.x, im.y, im.z, im.w};
    float mm[4] = {mk.x, mk.y, mk.z, mk.w};
    #pragma unroll
    for (int seg = 0; seg < NSEG; ++seg){
      int ps = bl*(NPOL*NSEG) + pol*NSEG + seg;
      w_t[(size_t)ps*PL + (size_t)r*NC + c] = make_float2(rr[seg], ii[seg]);
      m_t[(size_t)ps*PL + (size_t)c*NR + r] = mm[seg];
    }
  }
}

// pack_csm: batch b, all coils: c_t[cl][r][c].
__global__ __launch_bounds__(256) void pack_csm_kernel(
    int b,
    const float* __restrict__ csm_re, const float* __restrict__ csm_im,
    c32* __restrict__ c_t)
{
  int r = blockIdx.x;
  int c = threadIdx.x;
  const size_t PL = (size_t)NR*NC;
  size_t base = (((size_t)b*NR + r)*NC + c)*NCOIL;
  c32* cp = c_t + (size_t)r*NC + c;
  for (int cl = 0; cl < NCOIL; cl += 4){
    float4 re = *(const float4*)&csm_re[base + cl];
    float4 im = *(const float4*)&csm_im[base + cl];
    cp[(size_t)(cl+0)*PL] = make_float2(re.x, im.x);
    cp[(size_t)(cl+1)*PL] = make_float2(re.y, im.y);
    cp[(size_t)(cl+2)*PL] = make_float2(re.z, im.z);
    cp[(size_t)(cl+3)*PL] = make_float2(re.w, im.w);
  }
}

// ---------------------------------------------------------------------------
// stage A: row FFT of img*w*csm, write T1[p][k_c][r] fp16.
// Block: 16 rows (wave w, group g -> r = rt*16 + 4w + g), 4 FFTs per wave.
// grid: CH*NPOL*NSEG*16 blocks of 256
__global__ __launch_bounds__(256) void stageA_kernel(
    const c32* __restrict__ img_t, const c32* __restrict__ w_t,
    const c32* __restrict__ c_t, __half2* __restrict__ T1)
{
  __shared__ __half2 fsc[4][1024];
  __shared__ __half2 tile[NC*20];    // [k_c][16 rows], pad 20
  int tid = threadIdx.x;
  int l = tid & 15, g = (tid >> 4) & 3, w = tid >> 6;
  c32 tw[16]; mk_tw16(l, tw);
  int bid = blockIdx.x;
  int p  = bid >> 4;                 // ((cl*NPOL)+pol)*NSEG+seg
  int rt = bid & 15;
  int seg = p & 3, pol = (p>>2) & 1, cl = p >> 3;
  int r = rt*16 + 4*w + g;

  const c32* ir = img_t + ((size_t)pol*NR + r)*NC;
  const c32* wr = w_t  + ((size_t)(pol*NSEG+seg)*NR + r)*NC;
  const c32* cr = c_t  + ((size_t)cl*NR + r)*NC;
  c32 y[16];
  #pragma unroll
  for (int i = 0; i < 16; ++i){
    int c = 16*i + l;
    y[i] = cmul(cmul(ir[c], wr[c]), cr[c]);
  }
  fft256g<1>(y, tw, fsc[w], l, g);
  int rl = 4*w + g;
  #pragma unroll
  for (int j = 0; j < 16; ++j)
    tile[(l + 16*j)*20 + rl] = __floats2half2_rn(y[j].x, y[j].y);
  __syncthreads();
  // copy out: thread = k_c, 16 consecutive rows -> 64B contiguous
  __half2* tp = T1 + (size_t)p*(NR*NC) + (size_t)tid*NR + rt*16;
  const __half2* trow = tile + tid*20;
  #pragma unroll
  for (int k = 0; k < 4; ++k){
    __half2 h0 = trow[4*k+0], h1 = trow[4*k+1];
    __half2 h2 = trow[4*k+2], h3 = trow[4*k+3];
    uint4 q = make_uint4(*(unsigned*)&h0, *(unsigned*)&h1,
                         *(unsigned*)&h2, *(unsigned*)&h3);
    *(uint4*)(tp + 4*k) = q;
  }
}

// ---------------------------------------------------------------------------
// stage B: col FFT per seg (T-layout loads), K = sum(mask*X) in K-layout;
// per seg': re-mask, inverse col FFT, transpose tile, write T2[p][r][k_c].
// Block: 16 cols (col = ct*16 + 4w + g).  grid: CH*NPOL*16 blocks of 256
__global__ __launch_bounds__(256) void stageB_kernel(
    const __half2* __restrict__ T1, const float* __restrict__ m_t,
    __half2* __restrict__ T2)
{
  __shared__ __half2 fsc[4][1024];
  __shared__ __half2 tile[16*272];   // [col-local][r], pad 272
  int tid = threadIdx.x;
  int l = tid & 15, g = (tid >> 4) & 3, w = tid >> 6;
  c32 tw[16]; mk_tw16(l, tw);
  int bid = blockIdx.x;
  int ct = bid & 15;
  int gp = bid >> 4;                 // cl*NPOL + pol
  int pol = gp & 1;
  int col = ct*16 + 4*w + g;
  const size_t PL = (size_t)NR*NC;

  c32 K[16];
  #pragma unroll
  for (int j = 0; j < 16; ++j) K[j] = make_float2(0.f, 0.f);

  #pragma unroll 1
  for (int seg = 0; seg < NSEG; ++seg){
    const __half2* tp = T1 + ((size_t)(gp*NSEG+seg))*PL + (size_t)col*NR;
    const float*  mp = m_t + ((size_t)(pol*NSEG+seg)*NC + col)*NR;
    c32 y[16];
    #pragma unroll
    for (int i = 0; i < 16; ++i) y[i] = __half22float2(tp[16*i + l]);
    fft256g<1>(y, tw, fsc[w], l, g);
    #pragma unroll
    for (int j = 0; j < 16; ++j){
      float mv = mp[l + 16*j];
      K[j].x += mv*y[j].x;
      K[j].y += mv*y[j].y;
    }
  }
  #pragma unroll 1
  for (int seg = 0; seg < NSEG; ++seg){
    const float* mp = m_t + ((size_t)(pol*NSEG+seg)*NC + col)*NR;
    c32 y[16];
    #pragma unroll
    for (int j = 0; j < 16; ++j){
      float mv = mp[l + 16*j];
      y[j] = make_float2(K[j].x*mv, K[j].y*mv);
    }
    fft256g<-1>(y, tw, fsc[w], l, g);
    #pragma unroll
    for (int i = 0; i < 16; ++i)
      tile[(4*w+g)*272 + 16*i + l] = __floats2half2_rn(y[i].x*(1.0f/256.0f),
                                                       y[i].y*(1.0f/256.0f));
    __syncthreads();
    {
      unsigned pk[16];
      #pragma unroll
      for (int k = 0; k < 16; ++k){
        __half2 h = tile[k*272 + tid];
        pk[k] = *(unsigned*)&h;
      }
      uint4* dst = (uint4*)(T2 + ((size_t)(gp*NSEG+seg))*PL
                            + (size_t)tid*NC + ct*16);
      dst[0] = make_uint4(pk[0],  pk[1],  pk[2],  pk[3]);
      dst[1] = make_uint4(pk[4],  pk[5],  pk[6],  pk[7]);
      dst[2] = make_uint4(pk[8],  pk[9],  pk[10], pk[11]);
      dst[3] = make_uint4(pk[12], pk[13], pk[14], pk[15]);
    }
    __syncthreads();
  }
}

// ---------------------------------------------------------------------------
// stage C: row inverse FFT from T2 (K-layout loads), * conj(w)*conj(csm),
// accumulate ONE coil x 4 segs, write fp16 partial[coil][pol][r][c].
// Block: 16 rows (r = rt*16 + 4w + g).  grid: CH*NPOL*16 blocks of 256
__global__ __launch_bounds__(256) void stageC_part_kernel(
    const __half2* __restrict__ T2, const c32* __restrict__ w_t,
    const c32* __restrict__ c_t, __half2* __restrict__ part, int c0)
{
  __shared__ __half2 fsc[4][1024];
  int tid = threadIdx.x;
  int l = tid & 15, g = (tid >> 4) & 3, w = tid >> 6;
  c32 tw[16]; mk_tw16(l, tw);
  int bid = blockIdx.x;
  int rt = bid & 15, pol = (bid>>4) & 1, cl = bid >> 5;   // local coil
  int r = rt*16 + 4*w + g;
  const size_t PL = (size_t)NR*NC;

  c32 acc[16];
  #pragma unroll
  for (int i = 0; i < 16; ++i) acc[i] = make_float2(0.f, 0.f);

  #pragma unroll 1
  for (int seg = 0; seg < NSEG; ++seg){
    const __half2* rp = T2 + ((size_t)((cl*NPOL+pol)*NSEG+seg))*PL
                        + (size_t)r*NC;
    c32 y[16];
    #pragma unroll
    for (int j = 0; j < 16; ++j) y[j] = __half22float2(rp[l + 16*j]);
    fft256g<-1>(y, tw, fsc[w], l, g);
    const c32* wr = w_t + ((size_t)(pol*NSEG+seg)*NR + r)*NC;
    const c32* cr = c_t + ((size_t)cl*NR + r)*NC;
    #pragma unroll
    for (int i = 0; i < 16; ++i){
      int c = 16*i + l;
      c32 vv = cmulj(y[i], wr[c]);
      vv = cmulj(vv, cr[c]);
      acc[i].x += vv.x;
      acc[i].y += vv.y;
    }
  }
  __half2* pp = part + ((size_t)((c0+cl)*NPOL+pol))*PL + (size_t)r*NC;
  #pragma unroll
  for (int i = 0; i < 16; ++i)
    pp[16*i + l] = __floats2half2_rn(acc[i].x, acc[i].y);
}

// reduceC: out interior = sign * sum over 32 coil partials.
__global__ __launch_bounds__(256) void reduceC_kernel(
    int b, const __half2* __restrict__ part, float* __restrict__ out)
{
  int r = blockIdx.x, c = threadIdx.x;
  const size_t PL = (size_t)NR*NC;
  float2 s[NPOL];
  #pragma unroll
  for (int pol = 0; pol < NPOL; ++pol) s[pol] = make_float2(0.f, 0.f);
  #pragma unroll 4
  for (int ch = 0; ch < NCOIL; ++ch){
    #pragma unroll
    for (int pol = 0; pol < NPOL; ++pol){
      float2 f = __half22float2(part[((size_t)(ch*NPOL+pol))*PL + (size_t)r*NC + c]);
      s[pol].x += f.x; s[pol].y += f.y;
    }
  }
  float sgn = ((r + c) & 1) ? -1.0f : 1.0f;
  float4 o = make_float4(sgn*s[0].x, sgn*s[0].y, sgn*s[1].x, sgn*s[1].y);
  size_t oidx = (((size_t)b*OD + (r+OFF))*OD + (c+OFF));   // float4 units
  ((float4*)out)[oidx] = o;
}

// ---------------------------------------------------------------------------
extern "C" void kernel_launch(void* const* d_in, const int* in_sizes, int n_in,
                              void* d_out, int out_size, void* d_ws, size_t ws_size,
                              hipStream_t stream)
{
  (void)in_sizes; (void)n_in;
  const float* x_re   = (const float*)d_in[0];
  const float* x_im   = (const float*)d_in[1];
  const float* csm_re = (const float*)d_in[2];
  const float* csm_im = (const float*)d_in[3];
  const float* wm_re  = (const float*)d_in[4];
  const float* wm_im  = (const float*)d_in[5];
  const float* mask   = (const float*)d_in[6];

  const size_t PL = (size_t)NR*NC;
  const size_t imgB1 = (size_t)NPOL*PL*sizeof(c32);           // 1 MiB / batch
  const size_t wB1   = (size_t)NPOL*NSEG*PL*sizeof(c32);      // 4 MiB / batch
  const size_t mB1   = (size_t)NPOL*NSEG*PL*sizeof(float);    // 2 MiB / batch
  const size_t csmB1 = (size_t)NCOIL*PL*sizeof(c32);          // 16 MiB
  const size_t partB = (size_t)NCOIL*NPOL*PL*4;               // 16 MiB fp16
  const size_t coilB = (size_t)NPOL*NSEG*PL*4;                // 2 MiB fp16 / coil

  const size_t fixed = NB*(imgB1 + wB1 + mB1) + csmB1 + partB; // 60 MiB

  int CH = 32;
  while (CH > 4){
    if (fixed + (size_t)CH*2*coilB <= ws_size) break;
    CH >>= 1;
  }

  char* ws = (char*)d_ws;
  c32* img_t = (c32*)ws;
  c32* w_t   = (c32*)(ws + NB*imgB1);
  float* m_t = (float*)(ws + NB*(imgB1 + wB1));
  c32* c_t   = (c32*)(ws + NB*(imgB1 + wB1 + mB1));
  __half2* part = (__half2*)(ws + NB*(imgB1 + wB1 + mB1) + csmB1);
  __half2* T1 = (__half2*)(ws + fixed);
  __half2* T2 = (__half2*)(ws + fixed + (size_t)CH*coilB);

  float* out = (float*)d_out;
  zero_kernel<<<(out_size + 255)/256, 256, 0, stream>>>(out, out_size);

  pack_common_kernel<<<NB*NR, 256, 0, stream>>>(x_re, x_im, wm_re, wm_im,
                                                mask, img_t, w_t, m_t);
  for (int b = 0; b < NB; ++b){
    c32* img_b = img_t + (size_t)b*NPOL*PL;
    c32* w_b   = w_t   + (size_t)b*NPOL*NSEG*PL;
    float* m_b = m_t   + (size_t)b*NPOL*NSEG*PL;
    pack_csm_kernel<<<NR, 256, 0, stream>>>(b, csm_re, csm_im, c_t);
    for (int c0 = 0; c0 < NCOIL; c0 += CH){
      c32* c_b = c_t + (size_t)c0*PL;
      stageA_kernel<<<CH*NPOL*NSEG*16, 256, 0, stream>>>(img_b, w_b, c_b, T1);
      stageB_kernel<<<CH*NPOL*16, 256, 0, stream>>>(T1, m_b, T2);
      stageC_part_kernel<<<CH*NPOL*16, 256, 0, stream>>>(T2, w_b, c_b,
                                                         part, c0);
    }
    reduceC_kernel<<<NR, 256, 0, stream>>>(b, part, out);
  }
}